// Round 2
// baseline (416.035 us; speedup 1.0000x reference)
//
#include <hip/hip_runtime.h>
#include <math.h>

#define S_PAST 8192
#define S_TOT  8193
#define HID    4096
#define NH     32
#define HD     128
#define INNER  16384
#define CHUNK  256
#define NCHUNK 33            // ceil(8193/256)
#define ALPHA_ 7.483314773547883f       // sqrt(2*28)
#define INV_COEFF 0.08838834764831845f  // 1/(sqrt(128)*1)
#define EPS_ 1e-5f

// ---------------- LayerNorm: 1 block, 256 threads, H=4096 ----------------
__global__ __launch_bounds__(256) void ln_kernel(const float* __restrict__ xin,
                                                 const float* __restrict__ w,
                                                 const float* __restrict__ b,
                                                 float* __restrict__ out) {
    int tid = threadIdx.x;
    float xs[16];
    float s = 0.f, s2 = 0.f;
#pragma unroll
    for (int i = 0; i < 16; ++i) {
        float v = xin[tid + i * 256];
        xs[i] = v; s += v; s2 += v * v;
    }
    for (int off = 32; off; off >>= 1) {
        s  += __shfl_down(s, off, 64);
        s2 += __shfl_down(s2, off, 64);
    }
    __shared__ float rs[4], rs2[4];
    __shared__ float mu_s, ri_s;
    int wid = tid >> 6, lane = tid & 63;
    if (lane == 0) { rs[wid] = s; rs2[wid] = s2; }
    __syncthreads();
    if (tid == 0) {
        float S1 = rs[0] + rs[1] + rs[2] + rs[3];
        float S2 = rs2[0] + rs2[1] + rs2[2] + rs2[3];
        float mu = S1 / HID;
        float var = S2 / HID - mu * mu;
        mu_s = mu;
        ri_s = rsqrtf(var + EPS_);
    }
    __syncthreads();
    float mu = mu_s, ri = ri_s;
#pragma unroll
    for (int i = 0; i < 16; ++i) {
        int idx = tid + i * 256;
        out[idx] = (xs[i] - mu) * ri * w[idx] + b[idx];
    }
}

// ---------------- GEMV: y[r] = W[r,:]·x + b[r]; one row per block ----------------
// mode 0: plain; 1: += ALPHA*res[r]; 2: gelu(tanh)
__global__ __launch_bounds__(256) void gemv_kernel(
        const float* __restrict__ Wm, const float* __restrict__ bias,
        const float* __restrict__ x, float* __restrict__ y,
        const float* __restrict__ res, float* __restrict__ y2,
        int C, int mode) {
    int r = blockIdx.x;
    const float4* rowv = (const float4*)(Wm + (size_t)r * C);
    const float4* xv = (const float4*)x;
    int nvec = C >> 2;
    float acc = 0.f;
    for (int i = threadIdx.x; i < nvec; i += 256) {
        float4 wv = rowv[i];
        float4 xx = xv[i];
        acc += wv.x * xx.x + wv.y * xx.y + wv.z * xx.z + wv.w * xx.w;
    }
    for (int off = 32; off; off >>= 1) acc += __shfl_down(acc, off, 64);
    __shared__ float red[4];
    int wid = threadIdx.x >> 6, lane = threadIdx.x & 63;
    if (lane == 0) red[wid] = acc;
    __syncthreads();
    if (threadIdx.x == 0) {
        float t = red[0] + red[1] + red[2] + red[3] + bias[r];
        if (mode == 1) t += ALPHA_ * res[r];
        else if (mode == 2) {
            float u = t;
            t = 0.5f * u * (1.f + tanhf(0.7978845608028654f * (u + 0.044715f * u * u * u)));
        }
        y[r] = t;
        if (y2) y2[r] = t;
    }
}

// ---------------- RoPE + append new k/v row ----------------
__global__ __launch_bounds__(128) void rope_kv_kernel(
        const float* __restrict__ qkv, const float* __restrict__ cosc,
        const float* __restrict__ sinc, const int* __restrict__ pos_ids,
        const int* __restrict__ blk_ids, float* __restrict__ qrot,
        float* __restrict__ kout, float* __restrict__ vout) {
    int h = blockIdx.x, d = threadIdx.x;     // d in [0,128)
    int pos = pos_ids[0], blk = blk_ids[0];
    const float* qh = qkv + h * 384;         // [q(128) | k(128) | v(128)]
    float q = qh[d], k = qh[128 + d], v = qh[256 + d];
    int half = d >> 6;                       // 0 -> pos rope, 1 -> blk rope
    int i = d & 63;
    int p = half ? blk : pos;
    float c = cosc[p * 64 + i];
    float s = sinc[p * 64 + i];
    float qpart, kpart;
    int base = half * 64;
    if (i < 32) { qpart = -qh[base + i + 32]; kpart = -qh[128 + base + i + 32]; }
    else        { qpart =  qh[base + i - 32]; kpart =  qh[128 + base + i - 32]; }
    float qo = q * c + qpart * s;
    float ko = k * c + kpart * s;
    qrot[h * HD + d] = qo;
    size_t o = (size_t)S_PAST * HID + h * HD + d;
    kout[o] = ko;
    vout[o] = v;
}

// ---------------- attention partials: one (head, chunk) per block ----------------
__global__ __launch_bounds__(256) void attn_partial(
        const float* __restrict__ qrot, const float* __restrict__ kbase,
        const float* __restrict__ vbase, const unsigned char* __restrict__ mask,
        float* __restrict__ pm, float* __restrict__ pl, float* __restrict__ pctx) {
    int chunk = blockIdx.x, h = blockIdx.y;
    int s0 = chunk * CHUNK;
    int nrows = min(CHUNK, S_TOT - s0);
    __shared__ float qs[HD];
    __shared__ float sc[CHUNK];
    int tid = threadIdx.x;
    if (tid < HD) qs[tid] = qrot[h * HD + tid] * INV_COEFF;
    for (int r = tid; r < CHUNK; r += 256) sc[r] = -1e30f;
    __syncthreads();
    int wid = tid >> 6, lane = tid & 63;
    // each wave handles rows wid, wid+4, ...
    for (int r = wid; r < nrows; r += 4) {
        const float2* krow = (const float2*)(kbase + (size_t)(s0 + r) * HID + h * HD);
        float2 kk = krow[lane];
        float p = kk.x * qs[lane * 2] + kk.y * qs[lane * 2 + 1];
        for (int off = 32; off; off >>= 1) p += __shfl_down(p, off, 64);
        if (lane == 0) {
            float raw = p;
            if (mask[s0 + r]) raw = -10000.f;
            sc[r] = raw;
        }
    }
    __syncthreads();
    // block max
    float m = -1e30f;
    for (int r = tid; r < nrows; r += 256) m = fmaxf(m, sc[r]);
    for (int off = 32; off; off >>= 1) m = fmaxf(m, __shfl_down(m, off, 64));
    __shared__ float wm[4];
    if (lane == 0) wm[wid] = m;
    __syncthreads();
    m = fmaxf(fmaxf(wm[0], wm[1]), fmaxf(wm[2], wm[3]));
    // exp + sum
    float lsum = 0.f;
    for (int r = tid; r < nrows; r += 256) { float p = __expf(sc[r] - m); sc[r] = p; lsum += p; }
    for (int off = 32; off; off >>= 1) lsum += __shfl_down(lsum, off, 64);
    __shared__ float wl[4];
    if (lane == 0) wl[wid] = lsum;
    __syncthreads();
    float L = wl[0] + wl[1] + wl[2] + wl[3];
    // ctx partial: 256 threads = 2 row-halves x 128 dims
    int d = tid & 127;
    int hlf = tid >> 7;
    int rmid = (nrows + 1) >> 1;
    int rstart = hlf ? rmid : 0;
    int rend = hlf ? nrows : rmid;
    float accv = 0.f;
    for (int r = rstart; r < rend; ++r) {
        float p = sc[r];
        accv += p * vbase[(size_t)(s0 + r) * HID + h * HD + d];
    }
    __shared__ float ctxs[HD];
    if (hlf == 0) ctxs[d] = accv;
    __syncthreads();
    if (hlf == 1) ctxs[d] += accv;
    __syncthreads();
    int idx = h * NCHUNK + chunk;
    if (tid == 0) { pm[idx] = m; pl[idx] = L; }
    if (tid < HD) pctx[(size_t)idx * HD + tid] = ctxs[tid];
}

// ---------------- combine partials: one head per block ----------------
__global__ __launch_bounds__(128) void attn_combine(
        const float* __restrict__ pm, const float* __restrict__ pl,
        const float* __restrict__ pctx, float* __restrict__ ctx) {
    int h = blockIdx.x, tid = threadIdx.x;  // 128 threads = dims
    float M = -1e30f;
    for (int i = 0; i < NCHUNK; ++i) M = fmaxf(M, pm[h * NCHUNK + i]);
    float L = 0.f;
    for (int i = 0; i < NCHUNK; ++i) L += pl[h * NCHUNK + i] * __expf(pm[h * NCHUNK + i] - M);
    float acc = 0.f;
    for (int i = 0; i < NCHUNK; ++i) {
        float wgt = __expf(pm[h * NCHUNK + i] - M);
        acc += wgt * pctx[(size_t)(h * NCHUNK + i) * HD + tid];
    }
    ctx[h * HD + tid] = acc / L;
}

extern "C" void kernel_launch(void* const* d_in, const int* in_sizes, int n_in,
                              void* d_out, int out_size, void* d_ws, size_t ws_size,
                              hipStream_t stream) {
    const float* hidden = (const float*)d_in[0];
    const float* past_k = (const float*)d_in[1];
    const float* past_v = (const float*)d_in[2];
    const float* cosc = (const float*)d_in[3];
    const float* sinc = (const float*)d_in[4];
    const float* ln1w = (const float*)d_in[5];
    const float* ln1b = (const float*)d_in[6];
    const float* qkvw = (const float*)d_in[7];
    const float* qkvb = (const float*)d_in[8];
    const float* denw = (const float*)d_in[9];
    const float* denb = (const float*)d_in[10];
    const float* ln2w = (const float*)d_in[11];
    const float* ln2b = (const float*)d_in[12];
    const float* fc1w = (const float*)d_in[13];
    const float* fc1b = (const float*)d_in[14];
    const float* fc2w = (const float*)d_in[15];
    const float* fc2b = (const float*)d_in[16];
    const int* pos = (const int*)d_in[17];
    const int* blk = (const int*)d_in[18];
    const unsigned char* mask = (const unsigned char*)d_in[19];

    float* out_f = (float*)d_out;
    float* kout = out_f + HID;                    // [8193,32,128]
    float* vout = kout + (size_t)S_TOT * HID;     // [8193,32,128]

    float* ws = (float*)d_ws;
    float* resid1 = ws;                 // 4096
    float* qkvv   = ws + 4096;          // 12288
    float* qrot   = ws + 16384;         // 4096
    float* ctx    = ws + 20480;         // 4096
    float* hid2   = ws + 24576;         // 4096
    float* resid2 = ws + 28672;         // 4096
    float* mlpi   = ws + 32768;         // 16384
    float* pm     = ws + 53248;         // 1056
    float* pl     = ws + 54304;         // 1056
    float* pctx   = ws + 55360;         // 1056*128

    // KV cache copy (bit-exact d2d)
    hipMemcpyAsync(kout, past_k, (size_t)S_PAST * HID * sizeof(float),
                   hipMemcpyDeviceToDevice, stream);
    hipMemcpyAsync(vout, past_v, (size_t)S_PAST * HID * sizeof(float),
                   hipMemcpyDeviceToDevice, stream);

    ln_kernel<<<1, 256, 0, stream>>>(hidden, ln1w, ln1b, resid1);
    gemv_kernel<<<3 * HID, 256, 0, stream>>>(qkvw, qkvb, resid1, qkvv, nullptr, nullptr, HID, 0);
    rope_kv_kernel<<<NH, HD, 0, stream>>>(qkvv, cosc, sinc, pos, blk, qrot, kout, vout);
    attn_partial<<<dim3(NCHUNK, NH), 256, 0, stream>>>(qrot, kout, vout, mask, pm, pl, pctx);
    attn_combine<<<NH, HD, 0, stream>>>(pm, pl, pctx, ctx);
    gemv_kernel<<<HID, 256, 0, stream>>>(denw, denb, ctx, hid2, resid1, nullptr, HID, 1);
    ln_kernel<<<1, 256, 0, stream>>>(hid2, ln2w, ln2b, resid2);
    gemv_kernel<<<INNER, 256, 0, stream>>>(fc1w, fc1b, resid2, mlpi, nullptr, nullptr, HID, 2);
    gemv_kernel<<<HID, 256, 0, stream>>>(fc2w, fc2b, mlpi, out_f, resid2, nullptr, INNER, 1);
}

// Round 3
// 393.288 us; speedup vs baseline: 1.0578x; 1.0578x over previous
//
#include <hip/hip_runtime.h>
#include <math.h>

#define S_PAST 8192
#define S_TOT  8193
#define HID    4096
#define NH     32
#define HD     128
#define INNER  16384
#define CHUNK  256
#define NCHUNK 33            // ceil(8193/256)
#define ALPHA_ 7.483314773547883f       // sqrt(2*28)
#define INV_COEFF 0.08838834764831845f  // 1/(sqrt(128)*1)
#define EPS_ 1e-5f

// ---------------- LayerNorm: 1 block, 256 threads, H=4096 ----------------
__global__ __launch_bounds__(256) void ln_kernel(const float* __restrict__ xin,
                                                 const float* __restrict__ w,
                                                 const float* __restrict__ b,
                                                 float* __restrict__ out) {
    int tid = threadIdx.x;
    float xs[16];
    float s = 0.f, s2 = 0.f;
#pragma unroll
    for (int i = 0; i < 16; ++i) {
        float v = xin[tid + i * 256];
        xs[i] = v; s += v; s2 += v * v;
    }
    for (int off = 32; off; off >>= 1) {
        s  += __shfl_down(s, off, 64);
        s2 += __shfl_down(s2, off, 64);
    }
    __shared__ float rs[4], rs2[4];
    __shared__ float mu_s, ri_s;
    int wid = tid >> 6, lane = tid & 63;
    if (lane == 0) { rs[wid] = s; rs2[wid] = s2; }
    __syncthreads();
    if (tid == 0) {
        float S1 = rs[0] + rs[1] + rs[2] + rs[3];
        float S2 = rs2[0] + rs2[1] + rs2[2] + rs2[3];
        float mu = S1 / HID;
        float var = S2 / HID - mu * mu;
        mu_s = mu;
        ri_s = rsqrtf(var + EPS_);
    }
    __syncthreads();
    float mu = mu_s, ri = ri_s;
#pragma unroll
    for (int i = 0; i < 16; ++i) {
        int idx = tid + i * 256;
        out[idx] = (xs[i] - mu) * ri * w[idx] + b[idx];
    }
}

// ---------------- GEMV: one row per WAVE, 4 rows/block ----------------
// MODE 0: plain; 1: += ALPHA*res[r]; 2: gelu(tanh)
template <int C, int MODE>
__global__ __launch_bounds__(256) void gemv_kernel(
        const float* __restrict__ Wm, const float* __restrict__ bias,
        const float* __restrict__ x, float* __restrict__ y,
        const float* __restrict__ res) {
    int wid = threadIdx.x >> 6, lane = threadIdx.x & 63;
    int r = blockIdx.x * 4 + wid;
    const float4* __restrict__ rowv = (const float4*)(Wm + (size_t)r * C);
    const float4* __restrict__ xv = (const float4*)x;
    constexpr int IT = C / 4 / 64;   // 16 (C=4096) or 64 (C=16384)
    float acc0 = 0.f, acc1 = 0.f;
#pragma unroll
    for (int it = 0; it < IT; it += 2) {
        float4 w0 = rowv[lane + it * 64];
        float4 x0 = xv[lane + it * 64];
        float4 w1 = rowv[lane + (it + 1) * 64];
        float4 x1 = xv[lane + (it + 1) * 64];
        acc0 += w0.x * x0.x + w0.y * x0.y + w0.z * x0.z + w0.w * x0.w;
        acc1 += w1.x * x1.x + w1.y * x1.y + w1.z * x1.z + w1.w * x1.w;
    }
    float acc = acc0 + acc1;
    for (int off = 32; off; off >>= 1) acc += __shfl_down(acc, off, 64);
    if (lane == 0) {
        float t = acc + bias[r];
        if (MODE == 1) t += ALPHA_ * res[r];
        if (MODE == 2) {
            float u = t;
            t = 0.5f * u * (1.f + tanhf(0.7978845608028654f * (u + 0.044715f * u * u * u)));
        }
        y[r] = t;
    }
}

// ---------------- RoPE + append new k/v row ----------------
__global__ __launch_bounds__(128) void rope_kv_kernel(
        const float* __restrict__ qkv, const float* __restrict__ cosc,
        const float* __restrict__ sinc, const int* __restrict__ pos_ids,
        const int* __restrict__ blk_ids, float* __restrict__ qrot,
        float* __restrict__ kout, float* __restrict__ vout) {
    int h = blockIdx.x, d = threadIdx.x;     // d in [0,128)
    int pos = pos_ids[0], blk = blk_ids[0];
    const float* qh = qkv + h * 384;         // [q(128) | k(128) | v(128)]
    float q = qh[d], k = qh[128 + d], v = qh[256 + d];
    int half = d >> 6;                       // 0 -> pos rope, 1 -> blk rope
    int i = d & 63;
    int p = half ? blk : pos;
    float c = cosc[p * 64 + i];
    float s = sinc[p * 64 + i];
    float qpart, kpart;
    int base = half * 64;
    if (i < 32) { qpart = -qh[base + i + 32]; kpart = -qh[128 + base + i + 32]; }
    else        { qpart =  qh[base + i - 32]; kpart =  qh[128 + base + i - 32]; }
    float qo = q * c + qpart * s;
    float ko = k * c + kpart * s;
    qrot[h * HD + d] = qo;
    size_t o = (size_t)S_PAST * HID + h * HD + d;
    kout[o] = ko;
    vout[o] = v;
}

// ---- attention partials, fused with KV-cache copy: one (chunk, head) per block ----
// Reads past_k/past_v ONCE: writes through to kout/vout and uses the values
// in-register for scores / context. New row (s==S_PAST) read from kout/vout
// (written earlier by rope_kv_kernel).
__global__ __launch_bounds__(256) void attn_partial(
        const float* __restrict__ qrot, const float* __restrict__ pastk,
        const float* __restrict__ pastv, float* __restrict__ kout,
        float* __restrict__ vout, const unsigned char* __restrict__ mask,
        float* __restrict__ pm, float* __restrict__ pl, float* __restrict__ pctx) {
    int chunk = blockIdx.x, h = blockIdx.y;
    int s0 = chunk * CHUNK;
    int nrows = min(CHUNK, S_TOT - s0);
    __shared__ float qs[HD];
    __shared__ float sc[CHUNK];
    int tid = threadIdx.x;
    if (tid < HD) qs[tid] = qrot[h * HD + tid] * INV_COEFF;
    __syncthreads();
    int wid = tid >> 6, lane = tid & 63;
    // K phase: each wave handles rows wid, wid+4, ... ; copy + dot
    for (int r = wid; r < nrows; r += 4) {
        int srow = s0 + r;
        size_t gidx = (size_t)srow * HID + h * HD;
        float2 kk;
        if (srow < S_PAST) {
            kk = ((const float2*)(pastk + gidx))[lane];
            ((float2*)(kout + gidx))[lane] = kk;      // fused cache copy
        } else {
            kk = ((const float2*)(kout + gidx))[lane]; // new row from rope_kv
        }
        float p = kk.x * qs[lane * 2] + kk.y * qs[lane * 2 + 1];
        for (int off = 32; off; off >>= 1) p += __shfl_down(p, off, 64);
        if (lane == 0) sc[r] = mask[srow] ? -10000.f : p;
    }
    __syncthreads();
    // block max
    float m = -1e30f;
    for (int r = tid; r < nrows; r += 256) m = fmaxf(m, sc[r]);
    for (int off = 32; off; off >>= 1) m = fmaxf(m, __shfl_down(m, off, 64));
    __shared__ float wm[4];
    if (lane == 0) wm[wid] = m;
    __syncthreads();
    m = fmaxf(fmaxf(wm[0], wm[1]), fmaxf(wm[2], wm[3]));
    // exp + sum
    float lsum = 0.f;
    for (int r = tid; r < nrows; r += 256) { float p = __expf(sc[r] - m); sc[r] = p; lsum += p; }
    for (int off = 32; off; off >>= 1) lsum += __shfl_down(lsum, off, 64);
    __shared__ float wl[4];
    if (lane == 0) wl[wid] = lsum;
    __syncthreads();
    float L = wl[0] + wl[1] + wl[2] + wl[3];
    // V phase: 256 threads = 2 row-groups x 128 dims; copy + weighted sum
    int d = tid & 127;
    int g = tid >> 7;
    float accv = 0.f;
    for (int r = g; r < nrows; r += 2) {
        int srow = s0 + r;
        size_t gidx = (size_t)srow * HID + h * HD + d;
        float v;
        if (srow < S_PAST) {
            v = pastv[gidx];
            vout[gidx] = v;                            // fused cache copy
        } else {
            v = vout[gidx];
        }
        accv += sc[r] * v;
    }
    __shared__ float ctxs[HD];
    if (g == 0) ctxs[d] = accv;
    __syncthreads();
    if (g == 1) ctxs[d] += accv;
    __syncthreads();
    int idx = h * NCHUNK + chunk;
    if (tid == 0) { pm[idx] = m; pl[idx] = L; }
    if (tid < HD) pctx[(size_t)idx * HD + tid] = ctxs[tid];
}

// ---------------- combine partials: one head per block ----------------
__global__ __launch_bounds__(128) void attn_combine(
        const float* __restrict__ pm, const float* __restrict__ pl,
        const float* __restrict__ pctx, float* __restrict__ ctx) {
    int h = blockIdx.x, tid = threadIdx.x;  // 128 threads = dims
    float M = -1e30f;
    for (int i = 0; i < NCHUNK; ++i) M = fmaxf(M, pm[h * NCHUNK + i]);
    float L = 0.f;
    for (int i = 0; i < NCHUNK; ++i) L += pl[h * NCHUNK + i] * __expf(pm[h * NCHUNK + i] - M);
    float acc = 0.f;
    for (int i = 0; i < NCHUNK; ++i) {
        float wgt = __expf(pm[h * NCHUNK + i] - M);
        acc += wgt * pctx[(size_t)(h * NCHUNK + i) * HD + tid];
    }
    ctx[h * HD + tid] = acc / L;
}

extern "C" void kernel_launch(void* const* d_in, const int* in_sizes, int n_in,
                              void* d_out, int out_size, void* d_ws, size_t ws_size,
                              hipStream_t stream) {
    const float* hidden = (const float*)d_in[0];
    const float* past_k = (const float*)d_in[1];
    const float* past_v = (const float*)d_in[2];
    const float* cosc = (const float*)d_in[3];
    const float* sinc = (const float*)d_in[4];
    const float* ln1w = (const float*)d_in[5];
    const float* ln1b = (const float*)d_in[6];
    const float* qkvw = (const float*)d_in[7];
    const float* qkvb = (const float*)d_in[8];
    const float* denw = (const float*)d_in[9];
    const float* denb = (const float*)d_in[10];
    const float* ln2w = (const float*)d_in[11];
    const float* ln2b = (const float*)d_in[12];
    const float* fc1w = (const float*)d_in[13];
    const float* fc1b = (const float*)d_in[14];
    const float* fc2w = (const float*)d_in[15];
    const float* fc2b = (const float*)d_in[16];
    const int* pos = (const int*)d_in[17];
    const int* blk = (const int*)d_in[18];
    const unsigned char* mask = (const unsigned char*)d_in[19];

    float* out_f = (float*)d_out;
    float* kout = out_f + HID;                    // [8193,32,128]
    float* vout = kout + (size_t)S_TOT * HID;     // [8193,32,128]

    float* ws = (float*)d_ws;
    float* resid1 = ws;                 // 4096
    float* qkvv   = ws + 4096;          // 12288
    float* qrot   = ws + 16384;         // 4096
    float* ctx    = ws + 20480;         // 4096
    float* hid2   = ws + 24576;         // 4096
    float* resid2 = ws + 28672;         // 4096
    float* mlpi   = ws + 32768;         // 16384
    float* pm     = ws + 53248;         // 1056
    float* pl     = ws + 54304;         // 1056
    float* pctx   = ws + 55360;         // 1056*128

    ln_kernel<<<1, 256, 0, stream>>>(hidden, ln1w, ln1b, resid1);
    gemv_kernel<HID, 0><<<3 * HID / 4, 256, 0, stream>>>(qkvw, qkvb, resid1, qkvv, nullptr);
    rope_kv_kernel<<<NH, HD, 0, stream>>>(qkvv, cosc, sinc, pos, blk, qrot, kout, vout);
    attn_partial<<<dim3(NCHUNK, NH), 256, 0, stream>>>(qrot, past_k, past_v, kout, vout,
                                                       mask, pm, pl, pctx);
    attn_combine<<<NH, HD, 0, stream>>>(pm, pl, pctx, ctx);
    gemv_kernel<HID, 1><<<HID / 4, 256, 0, stream>>>(denw, denb, ctx, hid2, resid1);
    ln_kernel<<<1, 256, 0, stream>>>(hid2, ln2w, ln2b, resid2);
    gemv_kernel<HID, 2><<<INNER / 4, 256, 0, stream>>>(fc1w, fc1b, resid2, mlpi, nullptr);
    gemv_kernel<INNER, 1><<<HID / 4, 256, 0, stream>>>(fc2w, fc2b, mlpi, out_f, resid2);
}

// Round 4
// 341.472 us; speedup vs baseline: 1.2184x; 1.1517x over previous
//
#include <hip/hip_runtime.h>
#include <math.h>

#define S_PAST 8192
#define S_TOT  8193
#define HID    4096
#define NH     32
#define HD     128
#define INNER  16384
#define CH     32
#define NCH    257                       // ceil(8193/32)
#define S_PAD  (NCH * CH)                // 8224
#define ALPHA_ 7.483314773547883f        // sqrt(2*28)
#define INV_COEFF 0.08838834764831845f   // 1/(sqrt(128)*1)
#define EPS_ 1e-5f

// ---------------- LayerNorm: 1 block, 256 threads, H=4096 ----------------
__global__ __launch_bounds__(256) void ln_kernel(const float* __restrict__ xin,
                                                 const float* __restrict__ w,
                                                 const float* __restrict__ b,
                                                 float* __restrict__ out) {
    int tid = threadIdx.x;
    float xs[16];
    float s = 0.f, s2 = 0.f;
#pragma unroll
    for (int i = 0; i < 16; ++i) {
        float v = xin[tid + i * 256];
        xs[i] = v; s += v; s2 += v * v;
    }
    for (int off = 32; off; off >>= 1) {
        s  += __shfl_down(s, off, 64);
        s2 += __shfl_down(s2, off, 64);
    }
    __shared__ float rs[4], rs2[4];
    __shared__ float mu_s, ri_s;
    int wid = tid >> 6, lane = tid & 63;
    if (lane == 0) { rs[wid] = s; rs2[wid] = s2; }
    __syncthreads();
    if (tid == 0) {
        float S1 = rs[0] + rs[1] + rs[2] + rs[3];
        float S2 = rs2[0] + rs2[1] + rs2[2] + rs2[3];
        float mu = S1 / HID;
        float var = S2 / HID - mu * mu;
        mu_s = mu;
        ri_s = rsqrtf(var + EPS_);
    }
    __syncthreads();
    float mu = mu_s, ri = ri_s;
#pragma unroll
    for (int i = 0; i < 16; ++i) {
        int idx = tid + i * 256;
        out[idx] = (xs[i] - mu) * ri * w[idx] + b[idx];
    }
}

// ---------------- GEMV: one row per WAVE, 4 rows/block ----------------
// MODE 0: plain; 1: += ALPHA*res[r]; 2: gelu(tanh)
template <int C, int MODE>
__global__ __launch_bounds__(256) void gemv_kernel(
        const float* __restrict__ Wm, const float* __restrict__ bias,
        const float* __restrict__ x, float* __restrict__ y,
        const float* __restrict__ res) {
    int wid = threadIdx.x >> 6, lane = threadIdx.x & 63;
    int r = blockIdx.x * 4 + wid;
    const float4* __restrict__ rowv = (const float4*)(Wm + (size_t)r * C);
    const float4* __restrict__ xv = (const float4*)x;
    constexpr int IT = C / 4 / 64;   // 16 (C=4096) or 64 (C=16384)
    float acc0 = 0.f, acc1 = 0.f;
#pragma unroll
    for (int it = 0; it < IT; it += 2) {
        float4 w0 = rowv[lane + it * 64];
        float4 x0 = xv[lane + it * 64];
        float4 w1 = rowv[lane + (it + 1) * 64];
        float4 x1 = xv[lane + (it + 1) * 64];
        acc0 += w0.x * x0.x + w0.y * x0.y + w0.z * x0.z + w0.w * x0.w;
        acc1 += w1.x * x1.x + w1.y * x1.y + w1.z * x1.z + w1.w * x1.w;
    }
    float acc = acc0 + acc1;
    for (int off = 32; off; off >>= 1) acc += __shfl_down(acc, off, 64);
    if (lane == 0) {
        float t = acc + bias[r];
        if (MODE == 1) t += ALPHA_ * res[r];
        if (MODE == 2) {
            float u = t;
            t = 0.5f * u * (1.f + tanhf(0.7978845608028654f * (u + 0.044715f * u * u * u)));
        }
        y[r] = t;
    }
}

// ---------------- RoPE + append new k/v row (qrot pre-scaled) ----------------
__global__ __launch_bounds__(128) void rope_kv_kernel(
        const float* __restrict__ qkv, const float* __restrict__ cosc,
        const float* __restrict__ sinc, const int* __restrict__ pos_ids,
        const int* __restrict__ blk_ids, float* __restrict__ qrot,
        float* __restrict__ kout, float* __restrict__ vout) {
    int h = blockIdx.x, d = threadIdx.x;     // d in [0,128)
    int pos = pos_ids[0], blk = blk_ids[0];
    const float* qh = qkv + h * 384;         // [q(128) | k(128) | v(128)]
    float q = qh[d], k = qh[128 + d], v = qh[256 + d];
    int half = d >> 6;                       // 0 -> pos rope, 1 -> blk rope
    int i = d & 63;
    int p = half ? blk : pos;
    float c = cosc[p * 64 + i];
    float s = sinc[p * 64 + i];
    float qpart, kpart;
    int base = half * 64;
    if (i < 32) { qpart = -qh[base + i + 32]; kpart = -qh[128 + base + i + 32]; }
    else        { qpart =  qh[base + i - 32]; kpart =  qh[128 + base + i - 32]; }
    float qo = q * c + qpart * s;
    float ko = k * c + kpart * s;
    qrot[h * HD + d] = qo * INV_COEFF;       // fold 1/(sqrt(128)*coeff)
    size_t o = (size_t)S_PAST * HID + h * HD + d;
    kout[o] = ko;
    vout[o] = v;
}

// ---- k1: scores for ALL heads + fused K-cache copy; block = 32-row seq chunk ----
// thread t owns row elements [16t, 16t+16) -> head t/8. Contiguous 16KB row streams.
__global__ __launch_bounds__(256) void scores_kcopy(
        const float* __restrict__ qrot, const float* __restrict__ pastk,
        float* __restrict__ kout, const unsigned char* __restrict__ mask,
        float* __restrict__ scores) {
    int tid = threadIdx.x;
    int s0 = blockIdx.x * CH;
    const float4* __restrict__ qv = (const float4*)qrot;
    float4 q0 = qv[tid * 4 + 0], q1 = qv[tid * 4 + 1];
    float4 q2 = qv[tid * 4 + 2], q3 = qv[tid * 4 + 3];
    __shared__ float sc[CH][NH + 1];         // +1 pad: epilogue reads stride-NH
#pragma unroll 4
    for (int r = 0; r < CH; ++r) {
        int srow = s0 + r;
        float dot = 0.f;
        if (srow < S_TOT) {
            const float* kbase = (srow < S_PAST) ? pastk : kout;
            const float4* krow = (const float4*)(kbase + (size_t)srow * HID);
            float4 k0 = krow[tid * 4 + 0], k1 = krow[tid * 4 + 1];
            float4 k2 = krow[tid * 4 + 2], k3 = krow[tid * 4 + 3];
            if (srow < S_PAST) {
                float4* ko = (float4*)(kout + (size_t)srow * HID);
                ko[tid * 4 + 0] = k0; ko[tid * 4 + 1] = k1;
                ko[tid * 4 + 2] = k2; ko[tid * 4 + 3] = k3;
            }
            dot = q0.x * k0.x + q0.y * k0.y + q0.z * k0.z + q0.w * k0.w
                + q1.x * k1.x + q1.y * k1.y + q1.z * k1.z + q1.w * k1.w
                + q2.x * k2.x + q2.y * k2.y + q2.z * k2.z + q2.w * k2.w
                + q3.x * k3.x + q3.y * k3.y + q3.z * k3.z + q3.w * k3.w;
        }
        dot += __shfl_xor(dot, 1, 64);
        dot += __shfl_xor(dot, 2, 64);
        dot += __shfl_xor(dot, 4, 64);
        if ((tid & 7) == 0) sc[r][tid >> 3] = dot;
    }
    __syncthreads();
    for (int i = tid; i < CH * NH; i += 256) {
        int r = i & (CH - 1), h = i >> 5;
        int srow = s0 + r;
        float v;
        if (srow >= S_TOT) v = -1e30f;
        else v = mask[srow] ? -10000.f : sc[r][h];
        scores[(size_t)h * S_PAD + s0 + r] = v;
    }
}

// ---- k2: per-head softmax over S_PAD scores, normalized in place ----
__global__ __launch_bounds__(256) void softmax_kernel(float* __restrict__ scores) {
    int h = blockIdx.x, tid = threadIdx.x;
    float* row = scores + (size_t)h * S_PAD;
    float m = -1e30f;
    for (int i = tid; i < S_PAD; i += 256) m = fmaxf(m, row[i]);
    for (int off = 32; off; off >>= 1) m = fmaxf(m, __shfl_down(m, off, 64));
    __shared__ float wm[4], wl[4];
    __shared__ float Ms, Ls;
    int wid = tid >> 6, lane = tid & 63;
    if (lane == 0) wm[wid] = m;
    __syncthreads();
    if (tid == 0) Ms = fmaxf(fmaxf(wm[0], wm[1]), fmaxf(wm[2], wm[3]));
    __syncthreads();
    float M = Ms;
    float l = 0.f;
    for (int i = tid; i < S_PAD; i += 256) l += __expf(row[i] - M);
    for (int off = 32; off; off >>= 1) l += __shfl_down(l, off, 64);
    if (lane == 0) wl[wid] = l;
    __syncthreads();
    if (tid == 0) Ls = wl[0] + wl[1] + wl[2] + wl[3];
    __syncthreads();
    float inv = 1.f / Ls;
    for (int i = tid; i < S_PAD; i += 256) row[i] = __expf(row[i] - M) * inv;
}

// ---- k3: ctx partials for ALL heads + fused V-cache copy; block = 32-row chunk ----
__global__ __launch_bounds__(256) void pv_vcopy(
        const float* __restrict__ probs, const float* __restrict__ pastv,
        float* __restrict__ vout, float* __restrict__ pctx) {
    int tid = threadIdx.x;
    int s0 = blockIdx.x * CH;
    __shared__ float pl[NH][CH + 1];         // +1 pad
    for (int i = tid; i < NH * CH; i += 256) {
        int h = i >> 5, r = i & (CH - 1);
        pl[h][r] = probs[(size_t)h * S_PAD + s0 + r];
    }
    __syncthreads();
    int h = tid >> 3;
    float4 a0 = {0,0,0,0}, a1 = {0,0,0,0}, a2 = {0,0,0,0}, a3 = {0,0,0,0};
#pragma unroll 4
    for (int r = 0; r < CH; ++r) {
        int srow = s0 + r;
        if (srow >= S_TOT) break;            // uniform across block
        const float* vbase = (srow < S_PAST) ? pastv : vout;
        const float4* vrow = (const float4*)(vbase + (size_t)srow * HID);
        float4 v0 = vrow[tid * 4 + 0], v1 = vrow[tid * 4 + 1];
        float4 v2 = vrow[tid * 4 + 2], v3 = vrow[tid * 4 + 3];
        if (srow < S_PAST) {
            float4* vo = (float4*)(vout + (size_t)srow * HID);
            vo[tid * 4 + 0] = v0; vo[tid * 4 + 1] = v1;
            vo[tid * 4 + 2] = v2; vo[tid * 4 + 3] = v3;
        }
        float p = pl[h][r];
        a0.x += p * v0.x; a0.y += p * v0.y; a0.z += p * v0.z; a0.w += p * v0.w;
        a1.x += p * v1.x; a1.y += p * v1.y; a1.z += p * v1.z; a1.w += p * v1.w;
        a2.x += p * v2.x; a2.y += p * v2.y; a2.z += p * v2.z; a2.w += p * v2.w;
        a3.x += p * v3.x; a3.y += p * v3.y; a3.z += p * v3.z; a3.w += p * v3.w;
    }
    float4* pc = (float4*)(pctx + (size_t)blockIdx.x * HID);
    pc[tid * 4 + 0] = a0; pc[tid * 4 + 1] = a1;
    pc[tid * 4 + 2] = a2; pc[tid * 4 + 3] = a3;
}

// ---- k4: sum chunk partials -> ctx[4096] ----
__global__ __launch_bounds__(256) void ctx_combine(const float* __restrict__ pctx,
                                                   float* __restrict__ ctx) {
    int idx = blockIdx.x * 256 + threadIdx.x;   // 0..4095
    float a = 0.f;
    for (int c = 0; c < NCH; ++c) a += pctx[(size_t)c * HID + idx];
    ctx[idx] = a;
}

extern "C" void kernel_launch(void* const* d_in, const int* in_sizes, int n_in,
                              void* d_out, int out_size, void* d_ws, size_t ws_size,
                              hipStream_t stream) {
    const float* hidden = (const float*)d_in[0];
    const float* past_k = (const float*)d_in[1];
    const float* past_v = (const float*)d_in[2];
    const float* cosc = (const float*)d_in[3];
    const float* sinc = (const float*)d_in[4];
    const float* ln1w = (const float*)d_in[5];
    const float* ln1b = (const float*)d_in[6];
    const float* qkvw = (const float*)d_in[7];
    const float* qkvb = (const float*)d_in[8];
    const float* denw = (const float*)d_in[9];
    const float* denb = (const float*)d_in[10];
    const float* ln2w = (const float*)d_in[11];
    const float* ln2b = (const float*)d_in[12];
    const float* fc1w = (const float*)d_in[13];
    const float* fc1b = (const float*)d_in[14];
    const float* fc2w = (const float*)d_in[15];
    const float* fc2b = (const float*)d_in[16];
    const int* pos = (const int*)d_in[17];
    const int* blk = (const int*)d_in[18];
    const unsigned char* mask = (const unsigned char*)d_in[19];

    float* out_f = (float*)d_out;
    float* kout = out_f + HID;                    // [8193,32,128]
    float* vout = kout + (size_t)S_TOT * HID;     // [8193,32,128]

    float* ws = (float*)d_ws;
    float* resid1 = ws;                     // 4096
    float* qkvv   = ws + 4096;              // 12288
    float* qrot   = ws + 16384;             // 4096
    float* ctx    = ws + 20480;             // 4096
    float* hid2   = ws + 24576;             // 4096
    float* resid2 = ws + 28672;             // 4096
    float* mlpi   = ws + 32768;             // 16384
    float* scores = ws + 49152;             // NH*S_PAD = 263168
    float* pctx   = ws + 49152 + NH * S_PAD;  // NCH*HID = 1052672  (~5.3 MB total)

    ln_kernel<<<1, 256, 0, stream>>>(hidden, ln1w, ln1b, resid1);
    gemv_kernel<HID, 0><<<3 * HID / 4, 256, 0, stream>>>(qkvw, qkvb, resid1, qkvv, nullptr);
    rope_kv_kernel<<<NH, HD, 0, stream>>>(qkvv, cosc, sinc, pos, blk, qrot, kout, vout);
    scores_kcopy<<<NCH, 256, 0, stream>>>(qrot, past_k, kout, mask, scores);
    softmax_kernel<<<NH, 256, 0, stream>>>(scores);
    pv_vcopy<<<NCH, 256, 0, stream>>>(scores, past_v, vout, pctx);
    ctx_combine<<<16, 256, 0, stream>>>(pctx, ctx);
    gemv_kernel<HID, 1><<<HID / 4, 256, 0, stream>>>(denw, denb, ctx, hid2, resid1);
    ln_kernel<<<1, 256, 0, stream>>>(hid2, ln2w, ln2b, resid2);
    gemv_kernel<HID, 2><<<INNER / 4, 256, 0, stream>>>(fc1w, fc1b, resid2, mlpi, nullptr);
    gemv_kernel<INNER, 1><<<HID / 4, 256, 0, stream>>>(fc2w, fc2b, mlpi, out_f, resid2);
}

// Round 5
// 327.626 us; speedup vs baseline: 1.2698x; 1.0423x over previous
//
#include <hip/hip_runtime.h>
#include <math.h>

#define S_PAST 8192
#define S_TOT  8193
#define HID    4096
#define NH     32
#define HD     128
#define INNER  16384
#define CH     32
#define NCH    257                       // ceil(8193/32)
#define S_PAD  (NCH * CH)                // 8224
#define ALPHA_ 7.483314773547883f        // sqrt(2*28)
#define INV_COEFF 0.08838834764831845f   // 1/(sqrt(128)*1)
#define EPS_ 1e-5f

// ---------------- LayerNorm: 1 block, 256 threads, H=4096 ----------------
__global__ __launch_bounds__(256) void ln_kernel(const float* __restrict__ xin,
                                                 const float* __restrict__ w,
                                                 const float* __restrict__ b,
                                                 float* __restrict__ out) {
    int tid = threadIdx.x;
    float xs[16];
    float s = 0.f, s2 = 0.f;
#pragma unroll
    for (int i = 0; i < 16; ++i) {
        float v = xin[tid + i * 256];
        xs[i] = v; s += v; s2 += v * v;
    }
    for (int off = 32; off; off >>= 1) {
        s  += __shfl_down(s, off, 64);
        s2 += __shfl_down(s2, off, 64);
    }
    __shared__ float rs[4], rs2[4];
    __shared__ float mu_s, ri_s;
    int wid = tid >> 6, lane = tid & 63;
    if (lane == 0) { rs[wid] = s; rs2[wid] = s2; }
    __syncthreads();
    if (tid == 0) {
        float S1 = rs[0] + rs[1] + rs[2] + rs[3];
        float S2 = rs2[0] + rs2[1] + rs2[2] + rs2[3];
        float mu = S1 / HID;
        float var = S2 / HID - mu * mu;
        mu_s = mu;
        ri_s = rsqrtf(var + EPS_);
    }
    __syncthreads();
    float mu = mu_s, ri = ri_s;
#pragma unroll
    for (int i = 0; i < 16; ++i) {
        int idx = tid + i * 256;
        out[idx] = (xs[i] - mu) * ri * w[idx] + b[idx];
    }
}

// ---------------- GEMV: one row per WAVE, 4 rows/block ----------------
// MODE 0: plain; 1: += ALPHA*res[r]; 2: gelu(tanh)
template <int C, int MODE>
__global__ __launch_bounds__(256) void gemv_kernel(
        const float* __restrict__ Wm, const float* __restrict__ bias,
        const float* __restrict__ x, float* __restrict__ y,
        const float* __restrict__ res) {
    int wid = threadIdx.x >> 6, lane = threadIdx.x & 63;
    int r = blockIdx.x * 4 + wid;
    const float4* __restrict__ rowv = (const float4*)(Wm + (size_t)r * C);
    const float4* __restrict__ xv = (const float4*)x;
    constexpr int IT = C / 4 / 64;   // 16 (C=4096) or 64 (C=16384)
    float acc0 = 0.f, acc1 = 0.f;
#pragma unroll
    for (int it = 0; it < IT; it += 2) {
        float4 w0 = rowv[lane + it * 64];
        float4 x0 = xv[lane + it * 64];
        float4 w1 = rowv[lane + (it + 1) * 64];
        float4 x1 = xv[lane + (it + 1) * 64];
        acc0 += w0.x * x0.x + w0.y * x0.y + w0.z * x0.z + w0.w * x0.w;
        acc1 += w1.x * x1.x + w1.y * x1.y + w1.z * x1.z + w1.w * x1.w;
    }
    float acc = acc0 + acc1;
    for (int off = 32; off; off >>= 1) acc += __shfl_down(acc, off, 64);
    if (lane == 0) {
        float t = acc + bias[r];
        if (MODE == 1) t += ALPHA_ * res[r];
        if (MODE == 2) {
            float u = t;
            t = 0.5f * u * (1.f + tanhf(0.7978845608028654f * (u + 0.044715f * u * u * u)));
        }
        y[r] = t;
    }
}

// ---------------- RoPE + append new k/v row (qrot pre-scaled) ----------------
__global__ __launch_bounds__(128) void rope_kv_kernel(
        const float* __restrict__ qkv, const float* __restrict__ cosc,
        const float* __restrict__ sinc, const int* __restrict__ pos_ids,
        const int* __restrict__ blk_ids, float* __restrict__ qrot,
        float* __restrict__ kout, float* __restrict__ vout) {
    int h = blockIdx.x, d = threadIdx.x;     // d in [0,128)
    int pos = pos_ids[0], blk = blk_ids[0];
    const float* qh = qkv + h * 384;         // [q(128) | k(128) | v(128)]
    float q = qh[d], k = qh[128 + d], v = qh[256 + d];
    int half = d >> 6;                       // 0 -> pos rope, 1 -> blk rope
    int i = d & 63;
    int p = half ? blk : pos;
    float c = cosc[p * 64 + i];
    float s = sinc[p * 64 + i];
    float qpart, kpart;
    int base = half * 64;
    if (i < 32) { qpart = -qh[base + i + 32]; kpart = -qh[128 + base + i + 32]; }
    else        { qpart =  qh[base + i - 32]; kpart =  qh[128 + base + i - 32]; }
    float qo = q * c + qpart * s;
    float ko = k * c + kpart * s;
    qrot[h * HD + d] = qo * INV_COEFF;       // fold 1/(sqrt(128)*coeff)
    size_t o = (size_t)S_PAST * HID + h * HD + d;
    kout[o] = ko;
    vout[o] = v;
}

// ---- k1: scores + K-copy + per-chunk (m, sumexp). block = 32-row seq chunk.
// thread t loads float4 columns {t, t+256, t+512, t+768}: every global
// instruction is 1KB lane-contiguous. Column 256g+t belongs to head 8g+(t>>5).
__global__ __launch_bounds__(256) void scores_kcopy(
        const float* __restrict__ qrot, const float* __restrict__ pastk,
        float* __restrict__ kout, const unsigned char* __restrict__ mask,
        float* __restrict__ scores, float* __restrict__ pm, float* __restrict__ pe) {
    int tid = threadIdx.x;
    int s0 = blockIdx.x * CH;
    int a = tid >> 5;                        // 0..7: head sub-group
    const float4* __restrict__ qv = (const float4*)qrot;
    float4 q0 = qv[tid], q1 = qv[256 + tid], q2 = qv[512 + tid], q3 = qv[768 + tid];
    __shared__ float sc[CH][NH + 1];
#pragma unroll 4
    for (int r = 0; r < CH; ++r) {
        int srow = s0 + r;
        float d0 = -1e30f, d1 = 0.f, d2 = 0.f, d3 = 0.f;
        if (srow < S_TOT) {
            const float* kbase = (srow < S_PAST) ? pastk : kout;
            const float4* krow = (const float4*)(kbase + (size_t)srow * HID);
            float4 k0 = krow[tid], k1 = krow[256 + tid];
            float4 k2 = krow[512 + tid], k3 = krow[768 + tid];
            if (srow < S_PAST) {
                float4* ko = (float4*)(kout + (size_t)srow * HID);
                ko[tid] = k0; ko[256 + tid] = k1; ko[512 + tid] = k2; ko[768 + tid] = k3;
            }
            d0 = q0.x * k0.x + q0.y * k0.y + q0.z * k0.z + q0.w * k0.w;
            d1 = q1.x * k1.x + q1.y * k1.y + q1.z * k1.z + q1.w * k1.w;
            d2 = q2.x * k2.x + q2.y * k2.y + q2.z * k2.z + q2.w * k2.w;
            d3 = q3.x * k3.x + q3.y * k3.y + q3.z * k3.z + q3.w * k3.w;
        }
        // reduce over the 32 consecutive threads sharing 'a' (stays in half-wave)
#pragma unroll
        for (int off = 1; off < 32; off <<= 1) {
            d0 += __shfl_xor(d0, off, 64);
            d1 += __shfl_xor(d1, off, 64);
            d2 += __shfl_xor(d2, off, 64);
            d3 += __shfl_xor(d3, off, 64);
        }
        if ((tid & 31) == 0) {
            float v0, v1, v2, v3;
            if (srow >= S_TOT) { v0 = v1 = v2 = v3 = -1e30f; }
            else if (mask[srow]) { v0 = v1 = v2 = v3 = -10000.f; }
            else { v0 = d0; v1 = d1; v2 = d2; v3 = d3; }
            sc[r][a] = v0; sc[r][8 + a] = v1; sc[r][16 + a] = v2; sc[r][24 + a] = v3;
        }
    }
    __syncthreads();
    // write raw scores (coalesced 128B runs per head)
    for (int i = tid; i < CH * NH; i += 256) {
        int r = i & (CH - 1), h = i >> 5;
        scores[(size_t)h * S_PAD + s0 + r] = sc[r][h];
    }
    // per-chunk m / sumexp: thread i -> head i>>3, rows (i&7)+8k
    int h = tid >> 3, j = tid & 7;
    if (tid < 256) {
        float m = -1e30f;
#pragma unroll
        for (int k = 0; k < 4; ++k) m = fmaxf(m, sc[j + 8 * k][h]);
#pragma unroll
        for (int off = 1; off < 8; off <<= 1) m = fmaxf(m, __shfl_xor(m, off, 64));
        float e = 0.f;
#pragma unroll
        for (int k = 0; k < 4; ++k) e += __expf(sc[j + 8 * k][h] - m);
#pragma unroll
        for (int off = 1; off < 8; off <<= 1) e += __shfl_xor(e, off, 64);
        if (j == 0) { pm[h * NCH + blockIdx.x] = m; pe[h * NCH + blockIdx.x] = e; }
    }
}

// ---- k2: per-head global (M, 1/L) from chunk partials; 32 blocks ----
__global__ __launch_bounds__(256) void ml_combine(
        const float* __restrict__ pm, const float* __restrict__ pe,
        float* __restrict__ Mh, float* __restrict__ iLh) {
    int h = blockIdx.x, tid = threadIdx.x;
    float m = -1e30f;
    for (int c = tid; c < NCH; c += 256) m = fmaxf(m, pm[h * NCH + c]);
    for (int off = 32; off; off >>= 1) m = fmaxf(m, __shfl_down(m, off, 64));
    __shared__ float wm[4], wl[4];
    __shared__ float Ms;
    int wid = tid >> 6, lane = tid & 63;
    if (lane == 0) wm[wid] = m;
    __syncthreads();
    if (tid == 0) Ms = fmaxf(fmaxf(wm[0], wm[1]), fmaxf(wm[2], wm[3]));
    __syncthreads();
    float M = Ms;
    float l = 0.f;
    for (int c = tid; c < NCH; c += 256) l += pe[h * NCH + c] * __expf(pm[h * NCH + c] - M);
    for (int off = 32; off; off >>= 1) l += __shfl_down(l, off, 64);
    if (lane == 0) wl[wid] = l;
    __syncthreads();
    if (tid == 0) { Mh[h] = M; iLh[h] = 1.f / (wl[0] + wl[1] + wl[2] + wl[3]); }
}

// ---- k3: ctx partials + V-copy, exp fused. Same lane-contiguous column map ----
__global__ __launch_bounds__(256) void pv_vcopy(
        const float* __restrict__ scores, const float* __restrict__ Mh,
        const float* __restrict__ iLh, const float* __restrict__ pastv,
        float* __restrict__ vout, float* __restrict__ pctx) {
    int tid = threadIdx.x;
    int s0 = blockIdx.x * CH;
    int a = tid >> 5;
    __shared__ float pl[NH][CH + 1];
    for (int i = tid; i < NH * CH; i += 256) {
        int h = i >> 5, r = i & (CH - 1);
        pl[h][r] = __expf(scores[(size_t)h * S_PAD + s0 + r] - Mh[h]) * iLh[h];
    }
    __syncthreads();
    float4 a0 = {0,0,0,0}, a1 = {0,0,0,0}, a2 = {0,0,0,0}, a3 = {0,0,0,0};
#pragma unroll 4
    for (int r = 0; r < CH; ++r) {
        int srow = s0 + r;
        if (srow >= S_TOT) break;            // uniform across block
        const float* vbase = (srow < S_PAST) ? pastv : vout;
        const float4* vrow = (const float4*)(vbase + (size_t)srow * HID);
        float4 v0 = vrow[tid], v1 = vrow[256 + tid];
        float4 v2 = vrow[512 + tid], v3 = vrow[768 + tid];
        if (srow < S_PAST) {
            float4* vo = (float4*)(vout + (size_t)srow * HID);
            vo[tid] = v0; vo[256 + tid] = v1; vo[512 + tid] = v2; vo[768 + tid] = v3;
        }
        float p0 = pl[a][r], p1 = pl[8 + a][r], p2 = pl[16 + a][r], p3 = pl[24 + a][r];
        a0.x += p0 * v0.x; a0.y += p0 * v0.y; a0.z += p0 * v0.z; a0.w += p0 * v0.w;
        a1.x += p1 * v1.x; a1.y += p1 * v1.y; a1.z += p1 * v1.z; a1.w += p1 * v1.w;
        a2.x += p2 * v2.x; a2.y += p2 * v2.y; a2.z += p2 * v2.z; a2.w += p2 * v2.w;
        a3.x += p3 * v3.x; a3.y += p3 * v3.y; a3.z += p3 * v3.z; a3.w += p3 * v3.w;
    }
    float4* pc = (float4*)(pctx + (size_t)blockIdx.x * HID);
    pc[tid] = a0; pc[256 + tid] = a1; pc[512 + tid] = a2; pc[768 + tid] = a3;
}

// ---- k4: sum chunk partials -> ctx[4096] ----
__global__ __launch_bounds__(256) void ctx_combine(const float* __restrict__ pctx,
                                                   float* __restrict__ ctx) {
    int idx = blockIdx.x * 256 + threadIdx.x;   // 0..4095
    float a = 0.f;
    for (int c = 0; c < NCH; ++c) a += pctx[(size_t)c * HID + idx];
    ctx[idx] = a;
}

extern "C" void kernel_launch(void* const* d_in, const int* in_sizes, int n_in,
                              void* d_out, int out_size, void* d_ws, size_t ws_size,
                              hipStream_t stream) {
    const float* hidden = (const float*)d_in[0];
    const float* past_k = (const float*)d_in[1];
    const float* past_v = (const float*)d_in[2];
    const float* cosc = (const float*)d_in[3];
    const float* sinc = (const float*)d_in[4];
    const float* ln1w = (const float*)d_in[5];
    const float* ln1b = (const float*)d_in[6];
    const float* qkvw = (const float*)d_in[7];
    const float* qkvb = (const float*)d_in[8];
    const float* denw = (const float*)d_in[9];
    const float* denb = (const float*)d_in[10];
    const float* ln2w = (const float*)d_in[11];
    const float* ln2b = (const float*)d_in[12];
    const float* fc1w = (const float*)d_in[13];
    const float* fc1b = (const float*)d_in[14];
    const float* fc2w = (const float*)d_in[15];
    const float* fc2b = (const float*)d_in[16];
    const int* pos = (const int*)d_in[17];
    const int* blk = (const int*)d_in[18];
    const unsigned char* mask = (const unsigned char*)d_in[19];

    float* out_f = (float*)d_out;
    float* kout = out_f + HID;                    // [8193,32,128]
    float* vout = kout + (size_t)S_TOT * HID;     // [8193,32,128]

    float* ws = (float*)d_ws;
    float* resid1 = ws;                     // 4096
    float* qkvv   = ws + 4096;              // 12288
    float* qrot   = ws + 16384;             // 4096
    float* ctx    = ws + 20480;             // 4096
    float* hid2   = ws + 24576;             // 4096
    float* resid2 = ws + 28672;             // 4096
    float* mlpi   = ws + 32768;             // 16384
    float* scores = ws + 49152;             // NH*S_PAD = 263168
    float* pm     = ws + 312320;            // 32*257 = 8224
    float* pe     = ws + 320544;            // 8224
    float* Mh     = ws + 328768;            // 32
    float* iLh    = ws + 328800;            // 32
    float* pctx   = ws + 328832;            // NCH*HID = 1052672

    ln_kernel<<<1, 256, 0, stream>>>(hidden, ln1w, ln1b, resid1);
    gemv_kernel<HID, 0><<<3 * HID / 4, 256, 0, stream>>>(qkvw, qkvb, resid1, qkvv, nullptr);
    rope_kv_kernel<<<NH, HD, 0, stream>>>(qkvv, cosc, sinc, pos, blk, qrot, kout, vout);
    scores_kcopy<<<NCH, 256, 0, stream>>>(qrot, past_k, kout, mask, scores, pm, pe);
    ml_combine<<<NH, 256, 0, stream>>>(pm, pe, Mh, iLh);
    pv_vcopy<<<NCH, 256, 0, stream>>>(scores, Mh, iLh, past_v, vout, pctx);
    ctx_combine<<<16, 256, 0, stream>>>(pctx, ctx);
    gemv_kernel<HID, 1><<<HID / 4, 256, 0, stream>>>(denw, denb, ctx, hid2, resid1);
    ln_kernel<<<1, 256, 0, stream>>>(hid2, ln2w, ln2b, resid2);
    gemv_kernel<HID, 2><<<INNER / 4, 256, 0, stream>>>(fc1w, fc1b, resid2, mlpi, nullptr);
    gemv_kernel<INNER, 1><<<HID / 4, 256, 0, stream>>>(fc2w, fc2b, mlpi, out_f, resid2);
}

// Round 6
// 294.871 us; speedup vs baseline: 1.4109x; 1.1111x over previous
//
#include <hip/hip_runtime.h>
#include <math.h>

#define S_PAST 8192
#define S_TOT  8193
#define HID    4096
#define NH     32
#define HD     128
#define INNER  16384
#define CH     16
#define NCH    512                       // 512*16 = 8192; last block takes 17 rows
#define S_PAD  8224
#define ALPHA_ 7.483314773547883f        // sqrt(2*28)
#define INV_COEFF 0.08838834764831845f   // 1/(sqrt(128)*1)
#define EPS_ 1e-5f

// ---------------- LayerNorm: 1 block, 256 threads, H=4096 ----------------
__global__ __launch_bounds__(256) void ln_kernel(const float* __restrict__ xin,
                                                 const float* __restrict__ w,
                                                 const float* __restrict__ b,
                                                 float* __restrict__ out) {
    int tid = threadIdx.x;
    float xs[16];
    float s = 0.f, s2 = 0.f;
#pragma unroll
    for (int i = 0; i < 16; ++i) {
        float v = xin[tid + i * 256];
        xs[i] = v; s += v; s2 += v * v;
    }
    for (int off = 32; off; off >>= 1) {
        s  += __shfl_down(s, off, 64);
        s2 += __shfl_down(s2, off, 64);
    }
    __shared__ float rs[4], rs2[4];
    __shared__ float mu_s, ri_s;
    int wid = tid >> 6, lane = tid & 63;
    if (lane == 0) { rs[wid] = s; rs2[wid] = s2; }
    __syncthreads();
    if (tid == 0) {
        float S1 = rs[0] + rs[1] + rs[2] + rs[3];
        float S2 = rs2[0] + rs2[1] + rs2[2] + rs2[3];
        float mu = S1 / HID;
        float var = S2 / HID - mu * mu;
        mu_s = mu;
        ri_s = rsqrtf(var + EPS_);
    }
    __syncthreads();
    float mu = mu_s, ri = ri_s;
#pragma unroll
    for (int i = 0; i < 16; ++i) {
        int idx = tid + i * 256;
        out[idx] = (xs[i] - mu) * ri * w[idx] + b[idx];
    }
}

// ---------------- GEMV: one row per WAVE, 4 rows/block ----------------
// MODE 0: plain; 1: += ALPHA*res[r]; 2: gelu(tanh)
template <int C, int MODE>
__global__ __launch_bounds__(256) void gemv_kernel(
        const float* __restrict__ Wm, const float* __restrict__ bias,
        const float* __restrict__ x, float* __restrict__ y,
        const float* __restrict__ res) {
    int wid = threadIdx.x >> 6, lane = threadIdx.x & 63;
    int r = blockIdx.x * 4 + wid;
    const float4* __restrict__ rowv = (const float4*)(Wm + (size_t)r * C);
    const float4* __restrict__ xv = (const float4*)x;
    constexpr int IT = C / 4 / 64;   // 16 (C=4096) or 64 (C=16384)
    float acc0 = 0.f, acc1 = 0.f;
#pragma unroll
    for (int it = 0; it < IT; it += 2) {
        float4 w0 = rowv[lane + it * 64];
        float4 x0 = xv[lane + it * 64];
        float4 w1 = rowv[lane + (it + 1) * 64];
        float4 x1 = xv[lane + (it + 1) * 64];
        acc0 += w0.x * x0.x + w0.y * x0.y + w0.z * x0.z + w0.w * x0.w;
        acc1 += w1.x * x1.x + w1.y * x1.y + w1.z * x1.z + w1.w * x1.w;
    }
    float acc = acc0 + acc1;
    for (int off = 32; off; off >>= 1) acc += __shfl_down(acc, off, 64);
    if (lane == 0) {
        float t = acc + bias[r];
        if (MODE == 1) t += ALPHA_ * res[r];
        if (MODE == 2) {
            float u = t;
            t = 0.5f * u * (1.f + tanhf(0.7978845608028654f * (u + 0.044715f * u * u * u)));
        }
        y[r] = t;
    }
}

// ---------------- RoPE + append new k/v row (qrot pre-scaled) ----------------
__global__ __launch_bounds__(128) void rope_kv_kernel(
        const float* __restrict__ qkv, const float* __restrict__ cosc,
        const float* __restrict__ sinc, const int* __restrict__ pos_ids,
        const int* __restrict__ blk_ids, float* __restrict__ qrot,
        float* __restrict__ kout, float* __restrict__ vout) {
    int h = blockIdx.x, d = threadIdx.x;     // d in [0,128)
    int pos = pos_ids[0], blk = blk_ids[0];
    const float* qh = qkv + h * 384;         // [q(128) | k(128) | v(128)]
    float q = qh[d], k = qh[128 + d], v = qh[256 + d];
    int half = d >> 6;                       // 0 -> pos rope, 1 -> blk rope
    int i = d & 63;
    int p = half ? blk : pos;
    float c = cosc[p * 64 + i];
    float s = sinc[p * 64 + i];
    float qpart, kpart;
    int base = half * 64;
    if (i < 32) { qpart = -qh[base + i + 32]; kpart = -qh[128 + base + i + 32]; }
    else        { qpart =  qh[base + i - 32]; kpart =  qh[128 + base + i - 32]; }
    float qo = q * c + qpart * s;
    float ko = k * c + kpart * s;
    qrot[h * HD + d] = qo * INV_COEFF;       // fold 1/(sqrt(128)*coeff)
    size_t o = (size_t)S_PAST * HID + h * HD + d;
    kout[o] = ko;
    vout[o] = v;
}

// ---- k1: scores + K-copy + per-chunk (m, sumexp). block = 16/17-row chunk.
// thread t loads float4 columns {t, t+256, t+512, t+768}: 1KB lane-contiguous.
// Column 256g+t belongs to head 8g+(t>>5).
__global__ __launch_bounds__(256) void scores_kcopy(
        const float* __restrict__ qrot, const float* __restrict__ pastk,
        float* __restrict__ kout, const unsigned char* __restrict__ mask,
        float* __restrict__ scores, float* __restrict__ pm, float* __restrict__ pe) {
    int tid = threadIdx.x;
    int s0 = blockIdx.x * CH;
    int rows = (blockIdx.x == NCH - 1) ? (S_TOT - s0) : CH;   // 17 on last block
    int a = tid >> 5;                        // 0..7: head sub-group
    const float4* __restrict__ qv = (const float4*)qrot;
    float4 q0 = qv[tid], q1 = qv[256 + tid], q2 = qv[512 + tid], q3 = qv[768 + tid];
    __shared__ float sc[CH + 1][NH + 1];
#pragma unroll 4
    for (int r = 0; r < rows; ++r) {
        int srow = s0 + r;
        const float* kbase = (srow < S_PAST) ? pastk : kout;
        const float4* krow = (const float4*)(kbase + (size_t)srow * HID);
        float4 k0 = krow[tid], k1 = krow[256 + tid];
        float4 k2 = krow[512 + tid], k3 = krow[768 + tid];
        if (srow < S_PAST) {
            float4* ko = (float4*)(kout + (size_t)srow * HID);
            ko[tid] = k0; ko[256 + tid] = k1; ko[512 + tid] = k2; ko[768 + tid] = k3;
        }
        float d0 = q0.x * k0.x + q0.y * k0.y + q0.z * k0.z + q0.w * k0.w;
        float d1 = q1.x * k1.x + q1.y * k1.y + q1.z * k1.z + q1.w * k1.w;
        float d2 = q2.x * k2.x + q2.y * k2.y + q2.z * k2.z + q2.w * k2.w;
        float d3 = q3.x * k3.x + q3.y * k3.y + q3.z * k3.z + q3.w * k3.w;
#pragma unroll
        for (int off = 1; off < 32; off <<= 1) {
            d0 += __shfl_xor(d0, off, 64);
            d1 += __shfl_xor(d1, off, 64);
            d2 += __shfl_xor(d2, off, 64);
            d3 += __shfl_xor(d3, off, 64);
        }
        if ((tid & 31) == 0) {
            if (mask[srow]) { d0 = d1 = d2 = d3 = -10000.f; }
            sc[r][a] = d0; sc[r][8 + a] = d1; sc[r][16 + a] = d2; sc[r][24 + a] = d3;
        }
    }
    __syncthreads();
    // write raw scores
    for (int i = tid; i < rows * NH; i += 256) {
        int h = i & 31, r = i >> 5;
        scores[(size_t)h * S_PAD + s0 + r] = sc[r][h];
    }
    // per-chunk m / sumexp: 8 threads per head (j = lane-in-group)
    int h = tid >> 3, j = tid & 7;
    float m = -1e30f;
    for (int r = j; r < rows; r += 8) m = fmaxf(m, sc[r][h]);
#pragma unroll
    for (int off = 1; off < 8; off <<= 1) m = fmaxf(m, __shfl_xor(m, off, 64));
    float e = 0.f;
    for (int r = j; r < rows; r += 8) e += __expf(sc[r][h] - m);
#pragma unroll
    for (int off = 1; off < 8; off <<= 1) e += __shfl_xor(e, off, 64);
    if (j == 0) { pm[h * NCH + blockIdx.x] = m; pe[h * NCH + blockIdx.x] = e; }
}

// ---- k2: per-head global (M, 1/L) from chunk partials; 32 blocks ----
__global__ __launch_bounds__(256) void ml_combine(
        const float* __restrict__ pm, const float* __restrict__ pe,
        float* __restrict__ Mh, float* __restrict__ iLh) {
    int h = blockIdx.x, tid = threadIdx.x;
    float m = -1e30f;
    for (int c = tid; c < NCH; c += 256) m = fmaxf(m, pm[h * NCH + c]);
    for (int off = 32; off; off >>= 1) m = fmaxf(m, __shfl_down(m, off, 64));
    __shared__ float wm[4], wl[4];
    __shared__ float Ms;
    int wid = tid >> 6, lane = tid & 63;
    if (lane == 0) wm[wid] = m;
    __syncthreads();
    if (tid == 0) Ms = fmaxf(fmaxf(wm[0], wm[1]), fmaxf(wm[2], wm[3]));
    __syncthreads();
    float M = Ms;
    float l = 0.f;
    for (int c = tid; c < NCH; c += 256) l += pe[h * NCH + c] * __expf(pm[h * NCH + c] - M);
    for (int off = 32; off; off >>= 1) l += __shfl_down(l, off, 64);
    if (lane == 0) wl[wid] = l;
    __syncthreads();
    if (tid == 0) { Mh[h] = M; iLh[h] = 1.f / (wl[0] + wl[1] + wl[2] + wl[3]); }
}

// ---- k3: ctx partials + V-copy, exp fused. Same lane-contiguous column map ----
__global__ __launch_bounds__(256) void pv_vcopy(
        const float* __restrict__ scores, const float* __restrict__ Mh,
        const float* __restrict__ iLh, const float* __restrict__ pastv,
        float* __restrict__ vout, float* __restrict__ pctx) {
    int tid = threadIdx.x;
    int s0 = blockIdx.x * CH;
    int rows = (blockIdx.x == NCH - 1) ? (S_TOT - s0) : CH;
    int a = tid >> 5;
    __shared__ float pl[NH][CH + 2];
    for (int i = tid; i < rows * NH; i += 256) {
        int h = i & 31, r = i >> 5;
        pl[h][r] = __expf(scores[(size_t)h * S_PAD + s0 + r] - Mh[h]) * iLh[h];
    }
    __syncthreads();
    float4 a0 = {0,0,0,0}, a1 = {0,0,0,0}, a2 = {0,0,0,0}, a3 = {0,0,0,0};
#pragma unroll 4
    for (int r = 0; r < rows; ++r) {
        int srow = s0 + r;
        const float* vbase = (srow < S_PAST) ? pastv : vout;
        const float4* vrow = (const float4*)(vbase + (size_t)srow * HID);
        float4 v0 = vrow[tid], v1 = vrow[256 + tid];
        float4 v2 = vrow[512 + tid], v3 = vrow[768 + tid];
        if (srow < S_PAST) {
            float4* vo = (float4*)(vout + (size_t)srow * HID);
            vo[tid] = v0; vo[256 + tid] = v1; vo[512 + tid] = v2; vo[768 + tid] = v3;
        }
        float p0 = pl[a][r], p1 = pl[8 + a][r], p2 = pl[16 + a][r], p3 = pl[24 + a][r];
        a0.x += p0 * v0.x; a0.y += p0 * v0.y; a0.z += p0 * v0.z; a0.w += p0 * v0.w;
        a1.x += p1 * v1.x; a1.y += p1 * v1.y; a1.z += p1 * v1.z; a1.w += p1 * v1.w;
        a2.x += p2 * v2.x; a2.y += p2 * v2.y; a2.z += p2 * v2.z; a2.w += p2 * v2.w;
        a3.x += p3 * v3.x; a3.y += p3 * v3.y; a3.z += p3 * v3.z; a3.w += p3 * v3.w;
    }
    float4* pc = (float4*)(pctx + (size_t)blockIdx.x * HID);
    pc[tid] = a0; pc[256 + tid] = a1; pc[512 + tid] = a2; pc[768 + tid] = a3;
}

// ---- k4a: reduce 512 chunk partials -> 64 ----
__global__ __launch_bounds__(256) void ctx_reduce1(const float* __restrict__ pctx,
                                                   float* __restrict__ pctx2) {
    int b = blockIdx.x, tid = threadIdx.x;
    float4 a0 = {0,0,0,0}, a1 = {0,0,0,0}, a2 = {0,0,0,0}, a3 = {0,0,0,0};
#pragma unroll
    for (int c = 0; c < 8; ++c) {
        const float4* row = (const float4*)(pctx + (size_t)(b * 8 + c) * HID);
        float4 v0 = row[tid], v1 = row[256 + tid], v2 = row[512 + tid], v3 = row[768 + tid];
        a0.x += v0.x; a0.y += v0.y; a0.z += v0.z; a0.w += v0.w;
        a1.x += v1.x; a1.y += v1.y; a1.z += v1.z; a1.w += v1.w;
        a2.x += v2.x; a2.y += v2.y; a2.z += v2.z; a2.w += v2.w;
        a3.x += v3.x; a3.y += v3.y; a3.z += v3.z; a3.w += v3.w;
    }
    float4* o = (float4*)(pctx2 + (size_t)b * HID);
    o[tid] = a0; o[256 + tid] = a1; o[512 + tid] = a2; o[768 + tid] = a3;
}

// ---- k4b: reduce 64 -> ctx[4096] ----
__global__ __launch_bounds__(256) void ctx_reduce2(const float* __restrict__ pctx2,
                                                   float* __restrict__ ctx) {
    int idx = blockIdx.x * 256 + threadIdx.x;   // 0..4095
    float a = 0.f;
    for (int c = 0; c < 64; ++c) a += pctx2[(size_t)c * HID + idx];
    ctx[idx] = a;
}

extern "C" void kernel_launch(void* const* d_in, const int* in_sizes, int n_in,
                              void* d_out, int out_size, void* d_ws, size_t ws_size,
                              hipStream_t stream) {
    const float* hidden = (const float*)d_in[0];
    const float* past_k = (const float*)d_in[1];
    const float* past_v = (const float*)d_in[2];
    const float* cosc = (const float*)d_in[3];
    const float* sinc = (const float*)d_in[4];
    const float* ln1w = (const float*)d_in[5];
    const float* ln1b = (const float*)d_in[6];
    const float* qkvw = (const float*)d_in[7];
    const float* qkvb = (const float*)d_in[8];
    const float* denw = (const float*)d_in[9];
    const float* denb = (const float*)d_in[10];
    const float* ln2w = (const float*)d_in[11];
    const float* ln2b = (const float*)d_in[12];
    const float* fc1w = (const float*)d_in[13];
    const float* fc1b = (const float*)d_in[14];
    const float* fc2w = (const float*)d_in[15];
    const float* fc2b = (const float*)d_in[16];
    const int* pos = (const int*)d_in[17];
    const int* blk = (const int*)d_in[18];
    const unsigned char* mask = (const unsigned char*)d_in[19];

    float* out_f = (float*)d_out;
    float* kout = out_f + HID;                    // [8193,32,128]
    float* vout = kout + (size_t)S_TOT * HID;     // [8193,32,128]

    float* ws = (float*)d_ws;
    float* resid1 = ws;                     // 4096
    float* qkvv   = ws + 4096;              // 12288
    float* qrot   = ws + 16384;             // 4096
    float* ctx    = ws + 20480;             // 4096
    float* hid2   = ws + 24576;             // 4096
    float* resid2 = ws + 28672;             // 4096
    float* mlpi   = ws + 32768;             // 16384
    float* scores = ws + 49152;             // NH*S_PAD = 263168
    float* pm     = ws + 312320;            // 32*512 = 16384
    float* pe     = ws + 328704;            // 16384
    float* Mh     = ws + 345088;            // 32
    float* iLh    = ws + 345120;            // 32
    float* pctx   = ws + 345152;            // 512*4096 = 2097152
    float* pctx2  = ws + 2442304;           // 64*4096 = 262144  (~10.8 MB total)

    ln_kernel<<<1, 256, 0, stream>>>(hidden, ln1w, ln1b, resid1);
    gemv_kernel<HID, 0><<<3 * HID / 4, 256, 0, stream>>>(qkvw, qkvb, resid1, qkvv, nullptr);
    rope_kv_kernel<<<NH, HD, 0, stream>>>(qkvv, cosc, sinc, pos, blk, qrot, kout, vout);
    scores_kcopy<<<NCH, 256, 0, stream>>>(qrot, past_k, kout, mask, scores, pm, pe);
    ml_combine<<<NH, 256, 0, stream>>>(pm, pe, Mh, iLh);
    pv_vcopy<<<NCH, 256, 0, stream>>>(scores, Mh, iLh, past_v, vout, pctx);
    ctx_reduce1<<<64, 256, 0, stream>>>(pctx, pctx2);
    ctx_reduce2<<<16, 256, 0, stream>>>(pctx2, ctx);
    gemv_kernel<HID, 1><<<HID / 4, 256, 0, stream>>>(denw, denb, ctx, hid2, resid1);
    ln_kernel<<<1, 256, 0, stream>>>(hid2, ln2w, ln2b, resid2);
    gemv_kernel<HID, 2><<<INNER / 4, 256, 0, stream>>>(fc1w, fc1b, resid2, mlpi, nullptr);
    gemv_kernel<INNER, 1><<<HID / 4, 256, 0, stream>>>(fc2w, fc2b, mlpi, out_f, resid2);
}